// Round 12
// baseline (420.927 us; speedup 1.0000x reference)
//
#include <hip/hip_runtime.h>

typedef __bf16 bf16x8 __attribute__((ext_vector_type(8)));
typedef __bf16 bf16x4 __attribute__((ext_vector_type(4)));
typedef float  f32x4  __attribute__((ext_vector_type(4)));

#define MFMA16 __builtin_amdgcn_mfma_f32_16x16x32_bf16

__device__ __forceinline__ float fsig(float x)  { return 1.f / (1.f + __expf(-x)); }
__device__ __forceinline__ float ftanh(float x) { return 1.f - 2.f / (__expf(2.f * x) + 1.f); }

// B=512, T=20, D=1024, H=1024, 4H=4096. Layer 0 of the LSTM is dead code.
// Rows sorted by dlen descending -> dead work contiguous -> block early-exit.
// DETERMINISM INVARIANT: every ws location read is written earlier in the SAME
// call (per-row liveness guard in lstm_step epilogue; hA/hB/cst memset).
// LDS swizzle (all MFMA kernels): granule slot s (8 elems) of row r holds
// global granule s^(r&7) (XOR on low 3 bits). Writes LINEAR in lane
// (conflict-free, measured 0 in R11); swizzle applied to the GLOBAL source
// column; reads XOR the granule index with (row&7) -> ~2-way max.

// ---- sort batch rows by dlen descending (stable, deterministic) ----
__global__ __launch_bounds__(512) void sort_rows(
    const int* __restrict__ dlen, int* __restrict__ perm,
    int* __restrict__ dl_s, int* __restrict__ n_act)
{
    __shared__ int sdl[512];
    const int b = threadIdx.x;
    const int dl = dlen[b];
    sdl[b] = dl;
    __syncthreads();
    int pos = 0;
    for (int j = 0; j < 512; ++j) {
        const int dj = sdl[j];
        pos += (dj > dl) || (dj == dl && j < b);
    }
    perm[pos] = b;
    dl_s[pos] = dl;
    if (b < 20) {
        int cnt = 0;
        for (int j = 0; j < 512; ++j) cnt += (sdl[j] > b);
        n_act[b] = cnt;           // #rows active at step t (n_act[0]==512)
    }
}

// ---- convert layer-1 weights + W1 to bf16, bsum = b_ih[1]+b_hh[1] ----
__global__ __launch_bounds__(256) void convert_weights(
    const float* __restrict__ Wih, const float* __restrict__ Whh,
    const float* __restrict__ W1,  const float* __restrict__ bih,
    const float* __restrict__ bhh,
    __bf16* __restrict__ Wih1, __bf16* __restrict__ Whh1,
    __bf16* __restrict__ W1b,  float* __restrict__ bsum)
{
    const size_t L1 = 4096UL * 1024UL;
    size_t i = (size_t)blockIdx.x * 256 + threadIdx.x;   // 0 .. 1048575
    float4 a = *(const float4*)(Wih + L1 + i * 4);
    float4 b = *(const float4*)(Whh + L1 + i * 4);
    bf16x4 av = { (__bf16)a.x, (__bf16)a.y, (__bf16)a.z, (__bf16)a.w };
    bf16x4 bv = { (__bf16)b.x, (__bf16)b.y, (__bf16)b.z, (__bf16)b.w };
    *(bf16x4*)(Wih1 + i * 4) = av;
    *(bf16x4*)(Whh1 + i * 4) = bv;
    W1b[i] = (__bf16)W1[i];
    if (i < 4096) bsum[i] = bih[4096 + i] + bhh[4096 + i];
}

// ---- gather x in SORTED row order: xbf[t*512+sb] = [rel_emb | ent_emb] ----
__global__ __launch_bounds__(256) void gather_x(
    const int* __restrict__ ent, const int* __restrict__ rel,
    const float* __restrict__ ent_emb, const float* __restrict__ rel_emb,
    const int* __restrict__ perm, __bf16* __restrict__ xbf)
{
    int bid = blockIdx.x;              // sb*20 + t
    int sb = bid / 20, t = bid - sb * 20;
    int bo = perm[sb];
    int tid = threadIdx.x;
    int col = (tid & 127) * 4;
    const float* src = (tid < 128)
        ? (rel_emb + (size_t)rel[bo * 20 + t] * 512 + col)
        : (ent_emb + (size_t)ent[bo * 20 + t] * 512 + col);
    float4 v = *(const float4*)src;
    bf16x4 o = { (__bf16)v.x, (__bf16)v.y, (__bf16)v.z, (__bf16)v.w };
    int outcol = (tid < 128) ? col : (512 + col);
    *(bf16x4*)(xbf + (size_t)(t * 512 + sb) * 1024 + outcol) = o;
}

// ---- bf16 MFMA GEMM v3: dbuf, 1 barrier/iter, swizzled-source LDS ----
// Grid: x = colblock (n0), y = rowslab (m0) -> XCD = x%8 pins each 128-col
// B slice to one XCD's L2. SKIP: block dead if (m0&511) >= n_act[t].
template<bool RELU, bool SKIP>
__global__ __launch_bounds__(256) void gemm_bias(
    const __bf16* __restrict__ A, const __bf16* __restrict__ B,
    const float* __restrict__ bias, __bf16* __restrict__ C,
    int M, int N, int K, const int* __restrict__ nact)
{
    const int m0 = blockIdx.y * 128, n0 = blockIdx.x * 128;
    if (SKIP) {
        if ((m0 & 511) >= nact[m0 >> 9]) return;
    }
    __shared__ __bf16 As[2][128 * 64];
    __shared__ __bf16 Bs[2][128 * 64];
    const int tid = threadIdx.x;
    const int w = tid >> 6, lane = tid & 63;
    const int wr = (w >> 1) * 64, wc = (w & 1) * 64;
    const int srow = w * 32 + (lane >> 3);                 // staging row (+j*8)
    const int scol = (((lane & 7) ^ (lane >> 3)) << 3);    // swizzled source col
    const int wofs = srow * 64 + (lane & 7) * 8;           // LINEAR write (+j*512)

    f32x4 acc[4][4] = {};
    bf16x8 ar[4], br[4];

#pragma unroll
    for (int j = 0; j < 4; ++j) {
        ar[j] = *(const bf16x8*)(A + (size_t)(m0 + srow + j * 8) * K + scol);
        br[j] = *(const bf16x8*)(B + (size_t)(n0 + srow + j * 8) * K + scol);
    }
    for (int k0 = 0, i = 0; k0 < K; k0 += 64, ++i) {
        const int cur = i & 1;
#pragma unroll
        for (int j = 0; j < 4; ++j) {
            *(bf16x8*)&As[cur][wofs + j * 512] = ar[j];
            *(bf16x8*)&Bs[cur][wofs + j * 512] = br[j];
        }
        if (k0 + 64 < K) {
#pragma unroll
            for (int j = 0; j < 4; ++j) {
                ar[j] = *(const bf16x8*)(A + (size_t)(m0 + srow + j * 8) * K + k0 + 64 + scol);
                br[j] = *(const bf16x8*)(B + (size_t)(n0 + srow + j * 8) * K + k0 + 64 + scol);
            }
        }
        __syncthreads();
#pragma unroll
        for (int ks = 0; ks < 2; ++ks) {
            const int ko = (((ks * 4 + (lane >> 4)) ^ (lane & 7)) << 3);
            bf16x8 af[4], bb[4];
#pragma unroll
            for (int ii = 0; ii < 4; ++ii)
                af[ii] = *(const bf16x8*)&As[cur][(wr + ii * 16 + (lane & 15)) * 64 + ko];
#pragma unroll
            for (int j = 0; j < 4; ++j)
                bb[j] = *(const bf16x8*)&Bs[cur][(wc + j * 16 + (lane & 15)) * 64 + ko];
#pragma unroll
            for (int ii = 0; ii < 4; ++ii)
#pragma unroll
                for (int j = 0; j < 4; ++j)
                    acc[ii][j] = MFMA16(af[ii], bb[j], acc[ii][j], 0, 0, 0);
        }
    }
    const int rbase = m0 + wr + (lane >> 4) * 4;
    const int cbase = n0 + wc + (lane & 15);
#pragma unroll
    for (int j = 0; j < 4; ++j) {
        const int col = cbase + j * 16;
        const float bv = bias[col];
#pragma unroll
        for (int i = 0; i < 4; ++i)
#pragma unroll
            for (int r = 0; r < 4; ++r) {
                float v = acc[i][j][r] + bv;
                if (RELU) v = fmaxf(v, 0.f);
                C[(size_t)(rbase + i * 16 + r) * N + col] = (__bf16)v;
            }
    }
}

// ---- fused recurrent step v6: BK=128, 8 iters, dbuf 144KB, 1 barrier/iter ----
// Tile: 32 sorted rows x 256 gate-cols. Grid: x = colblock (XCD-pins Whh
// slice), y = rowblock (skip axis). 8 waves: rh=w>>2, cq=w&3; each wave holds
// all 4 gates of its (row,ch) in-register. Halved barrier count vs v5 (8 vs
// 16) with a 2x-deeper prefetch window: 9 in-flight b128 loads/thread issued
// a full MFMA phase (16 MFMAs) ahead of their LDS store.
__global__ __launch_bounds__(512, 2) void lstm_step(
    const __bf16* __restrict__ h_in, const __bf16* __restrict__ Whh,
    const __bf16* __restrict__ Xg, float* __restrict__ cst,
    __bf16* __restrict__ h_out, __bf16* __restrict__ sel,
    const int* __restrict__ dl_s, const int* __restrict__ perm,
    const int* __restrict__ n_act, int t)
{
    const int nt = n_act[t];
    const int m0 = blockIdx.y * 32;        // sorted batch-row block
    if (m0 >= nt) return;                  // whole slab dead at this step
    __shared__ __bf16 As[2][32 * 128];     // 2 x 8 KB
    __shared__ __bf16 Bs[2][256 * 128];    // 2 x 64 KB
    const int tid = threadIdx.x;
    const int w = tid >> 6, lane = tid & 63;
    const int j0 = blockIdx.x * 64;        // 64-channel block
    const int rh = w >> 2;                 // row half
    const int cq = w & 3;                  // channel quarter

    // B staging: thread -> ch row brow (0..63), slots seg & seg+8 of LDS rows
    // g*64+brow (g=0..3) -> 8 stores/iter. Source granules: s^(brow&7).
    const int brow = tid >> 3;
    const int seg  = tid & 7;
    const int bg0 = ((seg      ^ (brow & 7)) << 3);          // elems
    const int bg1 = (((seg + 8) ^ (brow & 7)) << 3);
    const __bf16* gB0 = Whh + (size_t)(0 * 1024 + j0 + brow) * 1024;
    const __bf16* gB1 = Whh + (size_t)(1 * 1024 + j0 + brow) * 1024;
    const __bf16* gB2 = Whh + (size_t)(2 * 1024 + j0 + brow) * 1024;
    const __bf16* gB3 = Whh + (size_t)(3 * 1024 + j0 + brow) * 1024;

    // A staging: thread -> row ar_ (0..31), slot aseg (0..15), 1 store/iter.
    const int ar_  = tid >> 4;
    const int aseg = tid & 15;
    const int ag   = ((aseg ^ (ar_ & 7)) << 3);              // elems
    const __bf16* gA = h_in + (size_t)(m0 + ar_) * 1024;

    f32x4 a0 = {0,0,0,0}, a1 = {0,0,0,0}, a2 = {0,0,0,0}, a3 = {0,0,0,0};
    bf16x8 rb0a, rb0b, rb1a, rb1b, rb2a, rb2b, rb3a, rb3b, ra;

    rb0a = *(const bf16x8*)(gB0 + bg0); rb0b = *(const bf16x8*)(gB0 + bg1);
    rb1a = *(const bf16x8*)(gB1 + bg0); rb1b = *(const bf16x8*)(gB1 + bg1);
    rb2a = *(const bf16x8*)(gB2 + bg0); rb2b = *(const bf16x8*)(gB2 + bg1);
    rb3a = *(const bf16x8*)(gB3 + bg0); rb3b = *(const bf16x8*)(gB3 + bg1);
    ra   = *(const bf16x8*)(gA + ag);

#pragma unroll
    for (int i = 0; i < 8; ++i) {
        const int cur = i & 1;
        const int k1 = (i + 1) * 128;
        *(bf16x8*)&Bs[cur][(0 * 64 + brow) * 128 + seg * 8]      = rb0a;
        *(bf16x8*)&Bs[cur][(0 * 64 + brow) * 128 + seg * 8 + 64] = rb0b;
        *(bf16x8*)&Bs[cur][(1 * 64 + brow) * 128 + seg * 8]      = rb1a;
        *(bf16x8*)&Bs[cur][(1 * 64 + brow) * 128 + seg * 8 + 64] = rb1b;
        *(bf16x8*)&Bs[cur][(2 * 64 + brow) * 128 + seg * 8]      = rb2a;
        *(bf16x8*)&Bs[cur][(2 * 64 + brow) * 128 + seg * 8 + 64] = rb2b;
        *(bf16x8*)&Bs[cur][(3 * 64 + brow) * 128 + seg * 8]      = rb3a;
        *(bf16x8*)&Bs[cur][(3 * 64 + brow) * 128 + seg * 8 + 64] = rb3b;
        *(bf16x8*)&As[cur][ar_ * 128 + aseg * 8] = ra;
        if (i < 7) {
            rb0a = *(const bf16x8*)(gB0 + bg0 + k1); rb0b = *(const bf16x8*)(gB0 + bg1 + k1);
            rb1a = *(const bf16x8*)(gB1 + bg0 + k1); rb1b = *(const bf16x8*)(gB1 + bg1 + k1);
            rb2a = *(const bf16x8*)(gB2 + bg0 + k1); rb2b = *(const bf16x8*)(gB2 + bg1 + k1);
            rb3a = *(const bf16x8*)(gB3 + bg0 + k1); rb3b = *(const bf16x8*)(gB3 + bg1 + k1);
            ra   = *(const bf16x8*)(gA + ag + k1);
        }
        __syncthreads();
#pragma unroll
        for (int ks = 0; ks < 4; ++ks) {
            const int ko = (((ks * 4 + (lane >> 4)) ^ (lane & 7)) << 3);
            bf16x8 av = *(const bf16x8*)&As[cur][(rh * 16 + (lane & 15)) * 128 + ko];
            bf16x8 b0 = *(const bf16x8*)&Bs[cur][(0 * 64 + cq * 16 + (lane & 15)) * 128 + ko];
            bf16x8 b1 = *(const bf16x8*)&Bs[cur][(1 * 64 + cq * 16 + (lane & 15)) * 128 + ko];
            bf16x8 b2 = *(const bf16x8*)&Bs[cur][(2 * 64 + cq * 16 + (lane & 15)) * 128 + ko];
            bf16x8 b3 = *(const bf16x8*)&Bs[cur][(3 * 64 + cq * 16 + (lane & 15)) * 128 + ko];
            a0 = MFMA16(av, b0, a0, 0, 0, 0);
            a1 = MFMA16(av, b1, a1, 0, 0, 0);
            a2 = MFMA16(av, b2, a2, 0, 0, 0);
            a3 = MFMA16(av, b3, a3, 0, 0, 0);
        }
    }
    // epilogue: lane owns 4 rows x 1 channel, gates = frags a0..a3 (i,f,g,o)
    const int ch  = j0 + cq * 16 + (lane & 15);
    const int rb_ = m0 + rh * 16 + (lane >> 4) * 4;
#pragma unroll
    for (int r = 0; r < 4; ++r) {
        const int b = rb_ + r;             // sorted row index
        if (b >= nt) continue;             // DEAD ROW: touch nothing (determinism)
        const __bf16* xg = Xg + (size_t)(t * 512 + b) * 4096 + ch;
        float gi = a0[r] + (float)xg[0];
        float gf = a1[r] + (float)xg[1024];
        float gg = a2[r] + (float)xg[2048];
        float go = a3[r] + (float)xg[3072];
        const size_t ix = (size_t)b * 1024 + ch;
        float cn = fsig(gf) * cst[ix] + fsig(gi) * ftanh(gg);
        cst[ix] = cn;
        float hv = fsig(go) * ftanh(cn);
        h_out[ix] = (__bf16)hv;
        if (dl_s[b] == t + 1)
            sel[(size_t)perm[b] * 1024 + ch] = (__bf16)hv;   // scatter to orig order
    }
}

// ---- final tiny layer: out[b,o] = relu(sum_k y1[b,k]*W2[o,k] + b2[o]) ----
__global__ __launch_bounds__(256) void mlp2(
    const __bf16* __restrict__ y1, const float* __restrict__ W2,
    const float* __restrict__ b2, float* __restrict__ out)
{
    int b = blockIdx.x, tid = threadIdx.x;
    float s0 = 0.f, s1 = 0.f;
    for (int k = tid; k < 1024; k += 256) {
        float v = (float)y1[(size_t)b * 1024 + k];
        s0 += v * W2[k];
        s1 += v * W2[1024 + k];
    }
#pragma unroll
    for (int o = 32; o > 0; o >>= 1) {
        s0 += __shfl_down(s0, o);
        s1 += __shfl_down(s1, o);
    }
    __shared__ float red[8];
    if ((tid & 63) == 0) { red[(tid >> 6) * 2] = s0; red[(tid >> 6) * 2 + 1] = s1; }
    __syncthreads();
    if (tid == 0) {
        float a0 = red[0] + red[2] + red[4] + red[6] + b2[0];
        float a1 = red[1] + red[3] + red[5] + red[7] + b2[1];
        out[b * 2 + 0] = fmaxf(a0, 0.f);
        out[b * 2 + 1] = fmaxf(a1, 0.f);
    }
}

extern "C" void kernel_launch(void* const* d_in, const int* in_sizes, int n_in,
                              void* d_out, int out_size, void* d_ws, size_t ws_size,
                              hipStream_t stream) {
    const int*   ent     = (const int*)d_in[0];
    const int*   rel     = (const int*)d_in[1];
    const int*   dlen    = (const int*)d_in[3];
    const float* ent_emb = (const float*)d_in[4];
    const float* rel_emb = (const float*)d_in[5];
    const float* Wih     = (const float*)d_in[6];
    const float* Whh     = (const float*)d_in[7];
    const float* bih     = (const float*)d_in[8];
    const float* bhh     = (const float*)d_in[9];
    const float* W1      = (const float*)d_in[10];
    const float* b1      = (const float*)d_in[11];
    const float* W2      = (const float*)d_in[12];
    const float* b2      = (const float*)d_in[13];
    float* out = (float*)d_out;

    char* ws = (char*)d_ws;
    size_t off = 0;
    auto alloc = [&](size_t bytes) -> void* {
        void* p = ws + off; off += (bytes + 255) & ~(size_t)255; return p;
    };
    __bf16* xbf   = (__bf16*)alloc(10240UL * 1024 * 2);  // [t*512+sb][1024]
    __bf16* Wih1  = (__bf16*)alloc(4096UL * 1024 * 2);
    __bf16* Whh1  = (__bf16*)alloc(4096UL * 1024 * 2);
    __bf16* W1b   = (__bf16*)alloc(1024UL * 1024 * 2);
    float*  bsum  = (float*) alloc(4096UL * 4);
    __bf16* Xg    = (__bf16*)alloc(10240UL * 4096 * 2);  // [t*512+sb][g*1024+ch]
    __bf16* hA    = (__bf16*)alloc(512UL * 1024 * 2);
    __bf16* hB    = (__bf16*)alloc(512UL * 1024 * 2);
    float*  cst   = (float*) alloc(512UL * 1024 * 4);
    __bf16* selb  = (__bf16*)alloc(512UL * 1024 * 2);    // ORIGINAL row order
    __bf16* y1b   = (__bf16*)alloc(512UL * 1024 * 2);
    int*    permb = (int*)   alloc(512 * 4);
    int*    dl_s  = (int*)   alloc(512 * 4);
    int*    n_act = (int*)   alloc(32 * 4);

    sort_rows<<<dim3(1), dim3(512), 0, stream>>>(dlen, permb, dl_s, n_act);
    convert_weights<<<dim3(4096), dim3(256), 0, stream>>>(
        Wih, Whh, W1, bih, bhh, Wih1, Whh1, W1b, bsum);
    gather_x<<<dim3(10240), dim3(256), 0, stream>>>(
        ent, rel, ent_emb, rel_emb, permb, xbf);
    // Xg = x @ W_ih[1]^T + (b_ih+b_hh); grid x=colblock (XCD-pins B slices),
    // y=rowslab (skip axis; dead 128-row slabs exit).
    gemm_bias<false, true><<<dim3(32, 80), dim3(256), 0, stream>>>(
        xbf, Wih1, bsum, Xg, 10240, 4096, 1024, n_act);

    hipMemsetAsync(hA, 0, 512UL * 1024 * 2, stream);
    hipMemsetAsync(hB, 0, 512UL * 1024 * 2, stream);
    hipMemsetAsync(cst, 0, 512UL * 1024 * 4, stream);

    for (int t = 0; t < 20; ++t) {
        const __bf16* hi = (t & 1) ? hB : hA;
        __bf16*       ho = (t & 1) ? hA : hB;
        // grid: x = colblock (Whh slice -> XCD pin), y = rowblock (skip axis)
        lstm_step<<<dim3(16, 16), dim3(512), 0, stream>>>(
            hi, Whh1, Xg, cst, ho, selb, dl_s, permb, n_act, t);
    }

    // y1 = relu(sel @ W1^T + b1)
    gemm_bias<true, false><<<dim3(8, 4), dim3(256), 0, stream>>>(
        selb, W1b, b1, y1b, 512, 1024, 1024, nullptr);
    mlp2<<<dim3(512), dim3(256), 0, stream>>>(y1b, W2, b2, out);
}

// Round 13
// 376.839 us; speedup vs baseline: 1.1170x; 1.1170x over previous
//
#include <hip/hip_runtime.h>

typedef __bf16 bf16x8 __attribute__((ext_vector_type(8)));
typedef __bf16 bf16x4 __attribute__((ext_vector_type(4)));
typedef float  f32x4  __attribute__((ext_vector_type(4)));

#define MFMA16 __builtin_amdgcn_mfma_f32_16x16x32_bf16

__device__ __forceinline__ float fsig(float x)  { return 1.f / (1.f + __expf(-x)); }
__device__ __forceinline__ float ftanh(float x) { return 1.f - 2.f / (__expf(2.f * x) + 1.f); }

// B=512, T=20, D=1024, H=1024, 4H=4096. Layer 0 of the LSTM is dead code.
// Rows sorted by dlen descending -> dead work contiguous -> block early-exit.
// DETERMINISM INVARIANT: every ws location read is written earlier in the SAME
// call (per-row liveness guard in lstm_step epilogue; hA/hB/cst memset).
// LDS swizzle (all MFMA kernels): granule slot s (8 elems) of row r holds
// global granule s^(r&7). Writes LINEAR in lane (conflict-free, measured 0 in
// R11); swizzle applied to the GLOBAL source column; reads XOR granule with
// (row&7) -> ~2-way max. BK=64 (R12: BK=128 regressed — deeper prefetch
// window costs more in VGPR/LDS-occupancy than saved barriers gain).

// ---- merged preprocessing: blocks 0..2047 convert weights, block 2048 sorts ----
// convert: layer-1 weights + W1 to bf16, bsum = b_ih[1]+b_hh[1].
// sort: rows by dlen descending (stable); n_act[t] = #rows with dlen > t.
__global__ __launch_bounds__(512) void prep(
    const float* __restrict__ Wih, const float* __restrict__ Whh,
    const float* __restrict__ W1,  const float* __restrict__ bih,
    const float* __restrict__ bhh, const int* __restrict__ dlen,
    __bf16* __restrict__ Wih1, __bf16* __restrict__ Whh1,
    __bf16* __restrict__ W1b,  float* __restrict__ bsum,
    int* __restrict__ perm, int* __restrict__ dl_s, int* __restrict__ n_act)
{
    const int tid = threadIdx.x;
    if (blockIdx.x < 2048) {
        const size_t L1 = 4096UL * 1024UL;
        size_t i = (size_t)blockIdx.x * 512 + tid;       // 0 .. 1048575
        float4 a = *(const float4*)(Wih + L1 + i * 4);
        float4 b = *(const float4*)(Whh + L1 + i * 4);
        bf16x4 av = { (__bf16)a.x, (__bf16)a.y, (__bf16)a.z, (__bf16)a.w };
        bf16x4 bv = { (__bf16)b.x, (__bf16)b.y, (__bf16)b.z, (__bf16)b.w };
        *(bf16x4*)(Wih1 + i * 4) = av;
        *(bf16x4*)(Whh1 + i * 4) = bv;
        W1b[i] = (__bf16)W1[i];
        if (i < 4096) bsum[i] = bih[4096 + i] + bhh[4096 + i];
    } else {
        __shared__ int sdl[512];
        const int b = tid;
        const int dl = dlen[b];
        sdl[b] = dl;
        __syncthreads();
        int pos = 0;
        for (int j = 0; j < 512; ++j) {
            const int dj = sdl[j];
            pos += (dj > dl) || (dj == dl && j < b);
        }
        perm[pos] = b;
        dl_s[pos] = dl;
        if (b < 20) {
            int cnt = 0;
            for (int j = 0; j < 512; ++j) cnt += (sdl[j] > b);
            n_act[b] = cnt;       // #rows active at step t (n_act[0]==512)
        }
    }
}

// ---- gather x in SORTED row order: xbf[t*512+sb] = [rel_emb | ent_emb] ----
__global__ __launch_bounds__(256) void gather_x(
    const int* __restrict__ ent, const int* __restrict__ rel,
    const float* __restrict__ ent_emb, const float* __restrict__ rel_emb,
    const int* __restrict__ perm, __bf16* __restrict__ xbf)
{
    int bid = blockIdx.x;              // sb*20 + t
    int sb = bid / 20, t = bid - sb * 20;
    int bo = perm[sb];
    int tid = threadIdx.x;
    int col = (tid & 127) * 4;
    const float* src = (tid < 128)
        ? (rel_emb + (size_t)rel[bo * 20 + t] * 512 + col)
        : (ent_emb + (size_t)ent[bo * 20 + t] * 512 + col);
    float4 v = *(const float4*)src;
    bf16x4 o = { (__bf16)v.x, (__bf16)v.y, (__bf16)v.z, (__bf16)v.w };
    int outcol = (tid < 128) ? col : (512 + col);
    *(bf16x4*)(xbf + (size_t)(t * 512 + sb) * 1024 + outcol) = o;
}

// ---- bf16 MFMA GEMM v3: dbuf, 1 barrier/iter, swizzled-source LDS ----
// Grid: x = colblock (n0), y = rowslab (m0) -> XCD = x%8 pins each 128-col
// B slice to one XCD's L2. SKIP: block dead if (m0&511) >= n_act[t].
template<bool RELU, bool SKIP>
__global__ __launch_bounds__(256) void gemm_bias(
    const __bf16* __restrict__ A, const __bf16* __restrict__ B,
    const float* __restrict__ bias, __bf16* __restrict__ C,
    int M, int N, int K, const int* __restrict__ nact)
{
    const int m0 = blockIdx.y * 128, n0 = blockIdx.x * 128;
    if (SKIP) {
        if ((m0 & 511) >= nact[m0 >> 9]) return;
    }
    __shared__ __bf16 As[2][128 * 64];
    __shared__ __bf16 Bs[2][128 * 64];
    const int tid = threadIdx.x;
    const int w = tid >> 6, lane = tid & 63;
    const int wr = (w >> 1) * 64, wc = (w & 1) * 64;
    const int srow = w * 32 + (lane >> 3);                 // staging row (+j*8)
    const int scol = (((lane & 7) ^ (lane >> 3)) << 3);    // swizzled source col
    const int wofs = srow * 64 + (lane & 7) * 8;           // LINEAR write (+j*512)

    f32x4 acc[4][4] = {};
    bf16x8 ar[4], br[4];

#pragma unroll
    for (int j = 0; j < 4; ++j) {
        ar[j] = *(const bf16x8*)(A + (size_t)(m0 + srow + j * 8) * K + scol);
        br[j] = *(const bf16x8*)(B + (size_t)(n0 + srow + j * 8) * K + scol);
    }
    for (int k0 = 0, i = 0; k0 < K; k0 += 64, ++i) {
        const int cur = i & 1;
#pragma unroll
        for (int j = 0; j < 4; ++j) {
            *(bf16x8*)&As[cur][wofs + j * 512] = ar[j];
            *(bf16x8*)&Bs[cur][wofs + j * 512] = br[j];
        }
        if (k0 + 64 < K) {
#pragma unroll
            for (int j = 0; j < 4; ++j) {
                ar[j] = *(const bf16x8*)(A + (size_t)(m0 + srow + j * 8) * K + k0 + 64 + scol);
                br[j] = *(const bf16x8*)(B + (size_t)(n0 + srow + j * 8) * K + k0 + 64 + scol);
            }
        }
        __syncthreads();
#pragma unroll
        for (int ks = 0; ks < 2; ++ks) {
            const int ko = (((ks * 4 + (lane >> 4)) ^ (lane & 7)) << 3);
            bf16x8 af[4], bb[4];
#pragma unroll
            for (int ii = 0; ii < 4; ++ii)
                af[ii] = *(const bf16x8*)&As[cur][(wr + ii * 16 + (lane & 15)) * 64 + ko];
#pragma unroll
            for (int j = 0; j < 4; ++j)
                bb[j] = *(const bf16x8*)&Bs[cur][(wc + j * 16 + (lane & 15)) * 64 + ko];
#pragma unroll
            for (int ii = 0; ii < 4; ++ii)
#pragma unroll
                for (int j = 0; j < 4; ++j)
                    acc[ii][j] = MFMA16(af[ii], bb[j], acc[ii][j], 0, 0, 0);
        }
    }
    const int rbase = m0 + wr + (lane >> 4) * 4;
    const int cbase = n0 + wc + (lane & 15);
#pragma unroll
    for (int j = 0; j < 4; ++j) {
        const int col = cbase + j * 16;
        const float bv = bias[col];
#pragma unroll
        for (int i = 0; i < 4; ++i)
#pragma unroll
            for (int r = 0; r < 4; ++r) {
                float v = acc[i][j][r] + bv;
                if (RELU) v = fmaxf(v, 0.f);
                C[(size_t)(rbase + i * 16 + r) * N + col] = (__bf16)v;
            }
    }
}

// ---- fused recurrent step v5 (R11-exact, proven best): BK=64, dbuf,
// swizzled-source LDS, XCD-pinned Whh, per-row determinism guard ----
// Tile: 32 sorted rows x 256 gate-cols. Grid: x = colblock (XCD pin),
// y = rowblock (skip axis). 8 waves: rh=w>>2, cq=w&3; each wave holds all
// 4 gates of its (row,ch) in-register.
__global__ __launch_bounds__(512) void lstm_step(
    const __bf16* __restrict__ h_in, const __bf16* __restrict__ Whh,
    const __bf16* __restrict__ Xg, float* __restrict__ cst,
    __bf16* __restrict__ h_out, __bf16* __restrict__ sel,
    const int* __restrict__ dl_s, const int* __restrict__ perm,
    const int* __restrict__ n_act, int t)
{
    const int nt = n_act[t];
    const int m0 = blockIdx.y * 32;        // sorted batch-row block
    if (m0 >= nt) return;                  // whole slab dead at this step
    __shared__ __bf16 As[2][32 * 64];      // 2 x 4 KB
    __shared__ __bf16 Bs[2][256 * 64];     // 2 x 32 KB
    const int tid = threadIdx.x;
    const int w = tid >> 6, lane = tid & 63;
    const int j0 = blockIdx.x * 64;        // 64-channel block
    const int rh = w >> 2;                 // row half
    const int cq = w & 3;                  // channel quarter

    // staging: thread -> LDS rows brow (A) / g*64+brow (B), linear slot seg.
    const int brow = tid >> 3;             // 0..63
    const int seg  = tid & 7;
    const int swc  = ((seg ^ (brow & 7)) << 3);   // swizzled global col granule
    const __bf16* gB = Whh + (size_t)(j0 + brow) * 1024 + swc;
    const __bf16* gA = h_in + (size_t)(m0 + brow) * 1024 + swc;  // tid<256 only

    f32x4 a0 = {0,0,0,0}, a1 = {0,0,0,0}, a2 = {0,0,0,0}, a3 = {0,0,0,0};
    bf16x8 rb0, rb1, rb2, rb3, ra;

    rb0 = *(const bf16x8*)(gB);
    rb1 = *(const bf16x8*)(gB + 1024UL * 1024);
    rb2 = *(const bf16x8*)(gB + 2048UL * 1024);
    rb3 = *(const bf16x8*)(gB + 3072UL * 1024);
    if (tid < 256) ra = *(const bf16x8*)(gA);

    for (int k0 = 0, i = 0; k0 < 1024; k0 += 64, ++i) {
        const int cur = i & 1;
        *(bf16x8*)&Bs[cur][(0 * 64 + brow) * 64 + seg * 8] = rb0;
        *(bf16x8*)&Bs[cur][(1 * 64 + brow) * 64 + seg * 8] = rb1;
        *(bf16x8*)&Bs[cur][(2 * 64 + brow) * 64 + seg * 8] = rb2;
        *(bf16x8*)&Bs[cur][(3 * 64 + brow) * 64 + seg * 8] = rb3;
        if (tid < 256) *(bf16x8*)&As[cur][brow * 64 + seg * 8] = ra;
        if (k0 + 64 < 1024) {
            rb0 = *(const bf16x8*)(gB + k0 + 64);
            rb1 = *(const bf16x8*)(gB + 1024UL * 1024 + k0 + 64);
            rb2 = *(const bf16x8*)(gB + 2048UL * 1024 + k0 + 64);
            rb3 = *(const bf16x8*)(gB + 3072UL * 1024 + k0 + 64);
            if (tid < 256) ra = *(const bf16x8*)(gA + k0 + 64);
        }
        __syncthreads();
#pragma unroll
        for (int ks = 0; ks < 2; ++ks) {
            const int ko = (((ks * 4 + (lane >> 4)) ^ (lane & 7)) << 3);
            bf16x8 av = *(const bf16x8*)&As[cur][(rh * 16 + (lane & 15)) * 64 + ko];
            bf16x8 b0 = *(const bf16x8*)&Bs[cur][(0 * 64 + cq * 16 + (lane & 15)) * 64 + ko];
            bf16x8 b1 = *(const bf16x8*)&Bs[cur][(1 * 64 + cq * 16 + (lane & 15)) * 64 + ko];
            bf16x8 b2 = *(const bf16x8*)&Bs[cur][(2 * 64 + cq * 16 + (lane & 15)) * 64 + ko];
            bf16x8 b3 = *(const bf16x8*)&Bs[cur][(3 * 64 + cq * 16 + (lane & 15)) * 64 + ko];
            a0 = MFMA16(av, b0, a0, 0, 0, 0);
            a1 = MFMA16(av, b1, a1, 0, 0, 0);
            a2 = MFMA16(av, b2, a2, 0, 0, 0);
            a3 = MFMA16(av, b3, a3, 0, 0, 0);
        }
    }
    // epilogue: lane owns 4 rows x 1 channel, gates = frags a0..a3 (i,f,g,o)
    const int ch  = j0 + cq * 16 + (lane & 15);
    const int rb_ = m0 + rh * 16 + (lane >> 4) * 4;
#pragma unroll
    for (int r = 0; r < 4; ++r) {
        const int b = rb_ + r;             // sorted row index
        if (b >= nt) continue;             // DEAD ROW: touch nothing (determinism)
        const __bf16* xg = Xg + (size_t)(t * 512 + b) * 4096 + ch;
        float gi = a0[r] + (float)xg[0];
        float gf = a1[r] + (float)xg[1024];
        float gg = a2[r] + (float)xg[2048];
        float go = a3[r] + (float)xg[3072];
        const size_t ix = (size_t)b * 1024 + ch;
        float cn = fsig(gf) * cst[ix] + fsig(gi) * ftanh(gg);
        cst[ix] = cn;
        float hv = fsig(go) * ftanh(cn);
        h_out[ix] = (__bf16)hv;
        if (dl_s[b] == t + 1)
            sel[(size_t)perm[b] * 1024 + ch] = (__bf16)hv;   // scatter to orig order
    }
}

// ---- final tiny layer: out[b,o] = relu(sum_k y1[b,k]*W2[o,k] + b2[o]) ----
__global__ __launch_bounds__(256) void mlp2(
    const __bf16* __restrict__ y1, const float* __restrict__ W2,
    const float* __restrict__ b2, float* __restrict__ out)
{
    int b = blockIdx.x, tid = threadIdx.x;
    float s0 = 0.f, s1 = 0.f;
    for (int k = tid; k < 1024; k += 256) {
        float v = (float)y1[(size_t)b * 1024 + k];
        s0 += v * W2[k];
        s1 += v * W2[1024 + k];
    }
#pragma unroll
    for (int o = 32; o > 0; o >>= 1) {
        s0 += __shfl_down(s0, o);
        s1 += __shfl_down(s1, o);
    }
    __shared__ float red[8];
    if ((tid & 63) == 0) { red[(tid >> 6) * 2] = s0; red[(tid >> 6) * 2 + 1] = s1; }
    __syncthreads();
    if (tid == 0) {
        float a0 = red[0] + red[2] + red[4] + red[6] + b2[0];
        float a1 = red[1] + red[3] + red[5] + red[7] + b2[1];
        out[b * 2 + 0] = fmaxf(a0, 0.f);
        out[b * 2 + 1] = fmaxf(a1, 0.f);
    }
}

extern "C" void kernel_launch(void* const* d_in, const int* in_sizes, int n_in,
                              void* d_out, int out_size, void* d_ws, size_t ws_size,
                              hipStream_t stream) {
    const int*   ent     = (const int*)d_in[0];
    const int*   rel     = (const int*)d_in[1];
    const int*   dlen    = (const int*)d_in[3];
    const float* ent_emb = (const float*)d_in[4];
    const float* rel_emb = (const float*)d_in[5];
    const float* Wih     = (const float*)d_in[6];
    const float* Whh     = (const float*)d_in[7];
    const float* bih     = (const float*)d_in[8];
    const float* bhh     = (const float*)d_in[9];
    const float* W1      = (const float*)d_in[10];
    const float* b1      = (const float*)d_in[11];
    const float* W2      = (const float*)d_in[12];
    const float* b2      = (const float*)d_in[13];
    float* out = (float*)d_out;

    char* ws = (char*)d_ws;
    size_t off = 0;
    auto alloc = [&](size_t bytes) -> void* {
        void* p = ws + off; off += (bytes + 255) & ~(size_t)255; return p;
    };
    __bf16* xbf   = (__bf16*)alloc(10240UL * 1024 * 2);  // [t*512+sb][1024]
    __bf16* Wih1  = (__bf16*)alloc(4096UL * 1024 * 2);
    __bf16* Whh1  = (__bf16*)alloc(4096UL * 1024 * 2);
    __bf16* W1b   = (__bf16*)alloc(1024UL * 1024 * 2);
    float*  bsum  = (float*) alloc(4096UL * 4);
    __bf16* Xg    = (__bf16*)alloc(10240UL * 4096 * 2);  // [t*512+sb][g*1024+ch]
    __bf16* hA    = (__bf16*)alloc(512UL * 1024 * 2);
    __bf16* hB    = (__bf16*)alloc(512UL * 1024 * 2);
    float*  cst   = (float*) alloc(512UL * 1024 * 4);
    __bf16* selb  = (__bf16*)alloc(512UL * 1024 * 2);    // ORIGINAL row order
    __bf16* y1b   = (__bf16*)alloc(512UL * 1024 * 2);
    int*    permb = (int*)   alloc(512 * 4);
    int*    dl_s  = (int*)   alloc(512 * 4);
    int*    n_act = (int*)   alloc(32 * 4);

    // merged convert + sort (independent work; sort hides under convert)
    prep<<<dim3(2049), dim3(512), 0, stream>>>(
        Wih, Whh, W1, bih, bhh, dlen,
        Wih1, Whh1, W1b, bsum, permb, dl_s, n_act);
    gather_x<<<dim3(10240), dim3(256), 0, stream>>>(
        ent, rel, ent_emb, rel_emb, permb, xbf);
    // Xg = x @ W_ih[1]^T + (b_ih+b_hh); grid x=colblock (XCD-pins B slices),
    // y=rowslab (skip axis; dead 128-row slabs exit).
    gemm_bias<false, true><<<dim3(32, 80), dim3(256), 0, stream>>>(
        xbf, Wih1, bsum, Xg, 10240, 4096, 1024, n_act);

    hipMemsetAsync(hA, 0, 512UL * 1024 * 2, stream);
    hipMemsetAsync(hB, 0, 512UL * 1024 * 2, stream);
    hipMemsetAsync(cst, 0, 512UL * 1024 * 4, stream);

    for (int t = 0; t < 20; ++t) {
        const __bf16* hi = (t & 1) ? hB : hA;
        __bf16*       ho = (t & 1) ? hA : hB;
        // grid: x = colblock (Whh slice -> XCD pin), y = rowblock (skip axis)
        lstm_step<<<dim3(16, 16), dim3(512), 0, stream>>>(
            hi, Whh1, Xg, cst, ho, selb, dl_s, permb, n_act, t);
    }

    // y1 = relu(sel @ W1^T + b1)
    gemm_bias<true, false><<<dim3(8, 4), dim3(256), 0, stream>>>(
        selb, W1b, b1, y1b, 512, 1024, 1024, nullptr);
    mlp2<<<dim3(512), dim3(256), 0, stream>>>(y1b, W2, b2, out);
}

// Round 14
// 359.265 us; speedup vs baseline: 1.1716x; 1.0489x over previous
//
#include <hip/hip_runtime.h>

typedef __bf16 bf16x8 __attribute__((ext_vector_type(8)));
typedef __bf16 bf16x4 __attribute__((ext_vector_type(4)));
typedef float  f32x4  __attribute__((ext_vector_type(4)));

#define MFMA16 __builtin_amdgcn_mfma_f32_16x16x32_bf16

__device__ __forceinline__ float fsig(float x)  { return 1.f / (1.f + __expf(-x)); }
__device__ __forceinline__ float ftanh(float x) { return 1.f - 2.f / (__expf(2.f * x) + 1.f); }

// B=512, T=20, D=1024, H=1024, 4H=4096. Layer 0 of the LSTM is dead code.
// Rows sorted by dlen descending -> dead work contiguous -> block early-exit.
// DETERMINISM INVARIANT: every ws location read is written earlier in the SAME
// call (per-row liveness guard in lstm_step epilogue; hA/hB/cst memset).
// LDS swizzle: granule slot s (8 elems) of row r holds global granule s^(r&7).
// Writes LINEAR in lane (conflict-free, measured 0); swizzle applied to the
// GLOBAL source column; reads XOR granule with (row&7) -> ~2-way max.
// Step kernel v7: tile 32x128, 256thr, grid(32,16)=512 blocks = 2 blocks/CU
// (v5 was 1 block/CU -> nothing hid per-iter stalls). Whh L2 traffic unchanged.

// ---- merged preprocessing: blocks 0..2047 convert weights, block 2048 sorts ----
__global__ __launch_bounds__(512) void prep(
    const float* __restrict__ Wih, const float* __restrict__ Whh,
    const float* __restrict__ W1,  const float* __restrict__ bih,
    const float* __restrict__ bhh, const int* __restrict__ dlen,
    __bf16* __restrict__ Wih1, __bf16* __restrict__ Whh1,
    __bf16* __restrict__ W1b,  float* __restrict__ bsum,
    int* __restrict__ perm, int* __restrict__ dl_s, int* __restrict__ n_act)
{
    const int tid = threadIdx.x;
    if (blockIdx.x < 2048) {
        const size_t L1 = 4096UL * 1024UL;
        size_t i = (size_t)blockIdx.x * 512 + tid;       // 0 .. 1048575
        float4 a = *(const float4*)(Wih + L1 + i * 4);
        float4 b = *(const float4*)(Whh + L1 + i * 4);
        bf16x4 av = { (__bf16)a.x, (__bf16)a.y, (__bf16)a.z, (__bf16)a.w };
        bf16x4 bv = { (__bf16)b.x, (__bf16)b.y, (__bf16)b.z, (__bf16)b.w };
        *(bf16x4*)(Wih1 + i * 4) = av;
        *(bf16x4*)(Whh1 + i * 4) = bv;
        W1b[i] = (__bf16)W1[i];
        if (i < 4096) bsum[i] = bih[4096 + i] + bhh[4096 + i];
    } else {
        __shared__ int sdl[512];
        const int b = tid;
        const int dl = dlen[b];
        sdl[b] = dl;
        __syncthreads();
        int pos = 0;
        for (int j = 0; j < 512; ++j) {
            const int dj = sdl[j];
            pos += (dj > dl) || (dj == dl && j < b);
        }
        perm[pos] = b;
        dl_s[pos] = dl;
        if (b < 20) {
            int cnt = 0;
            for (int j = 0; j < 512; ++j) cnt += (sdl[j] > b);
            n_act[b] = cnt;       // #rows active at step t (n_act[0]==512)
        }
    }
}

// ---- gather x in SORTED row order: xbf[t*512+sb] = [rel_emb | ent_emb] ----
__global__ __launch_bounds__(256) void gather_x(
    const int* __restrict__ ent, const int* __restrict__ rel,
    const float* __restrict__ ent_emb, const float* __restrict__ rel_emb,
    const int* __restrict__ perm, __bf16* __restrict__ xbf)
{
    int bid = blockIdx.x;              // sb*20 + t
    int sb = bid / 20, t = bid - sb * 20;
    int bo = perm[sb];
    int tid = threadIdx.x;
    int col = (tid & 127) * 4;
    const float* src = (tid < 128)
        ? (rel_emb + (size_t)rel[bo * 20 + t] * 512 + col)
        : (ent_emb + (size_t)ent[bo * 20 + t] * 512 + col);
    float4 v = *(const float4*)src;
    bf16x4 o = { (__bf16)v.x, (__bf16)v.y, (__bf16)v.z, (__bf16)v.w };
    int outcol = (tid < 128) ? col : (512 + col);
    *(bf16x4*)(xbf + (size_t)(t * 512 + sb) * 1024 + outcol) = o;
}

// ---- bf16 MFMA GEMM v3 (R11-exact): dbuf, 1 barrier/iter, swizzled LDS ----
// Grid: x = colblock (n0), y = rowslab (m0) -> XCD = x%8 pins B slices.
// SKIP: block dead if (m0&511) >= n_act[t].
template<bool RELU, bool SKIP>
__global__ __launch_bounds__(256) void gemm_bias(
    const __bf16* __restrict__ A, const __bf16* __restrict__ B,
    const float* __restrict__ bias, __bf16* __restrict__ C,
    int M, int N, int K, const int* __restrict__ nact)
{
    const int m0 = blockIdx.y * 128, n0 = blockIdx.x * 128;
    if (SKIP) {
        if ((m0 & 511) >= nact[m0 >> 9]) return;
    }
    __shared__ __bf16 As[2][128 * 64];
    __shared__ __bf16 Bs[2][128 * 64];
    const int tid = threadIdx.x;
    const int w = tid >> 6, lane = tid & 63;
    const int wr = (w >> 1) * 64, wc = (w & 1) * 64;
    const int srow = w * 32 + (lane >> 3);                 // staging row (+j*8)
    const int scol = (((lane & 7) ^ (lane >> 3)) << 3);    // swizzled source col
    const int wofs = srow * 64 + (lane & 7) * 8;           // LINEAR write (+j*512)

    f32x4 acc[4][4] = {};
    bf16x8 ar[4], br[4];

#pragma unroll
    for (int j = 0; j < 4; ++j) {
        ar[j] = *(const bf16x8*)(A + (size_t)(m0 + srow + j * 8) * K + scol);
        br[j] = *(const bf16x8*)(B + (size_t)(n0 + srow + j * 8) * K + scol);
    }
    for (int k0 = 0, i = 0; k0 < K; k0 += 64, ++i) {
        const int cur = i & 1;
#pragma unroll
        for (int j = 0; j < 4; ++j) {
            *(bf16x8*)&As[cur][wofs + j * 512] = ar[j];
            *(bf16x8*)&Bs[cur][wofs + j * 512] = br[j];
        }
        if (k0 + 64 < K) {
#pragma unroll
            for (int j = 0; j < 4; ++j) {
                ar[j] = *(const bf16x8*)(A + (size_t)(m0 + srow + j * 8) * K + k0 + 64 + scol);
                br[j] = *(const bf16x8*)(B + (size_t)(n0 + srow + j * 8) * K + k0 + 64 + scol);
            }
        }
        __syncthreads();
#pragma unroll
        for (int ks = 0; ks < 2; ++ks) {
            const int ko = (((ks * 4 + (lane >> 4)) ^ (lane & 7)) << 3);
            bf16x8 af[4], bb[4];
#pragma unroll
            for (int ii = 0; ii < 4; ++ii)
                af[ii] = *(const bf16x8*)&As[cur][(wr + ii * 16 + (lane & 15)) * 64 + ko];
#pragma unroll
            for (int j = 0; j < 4; ++j)
                bb[j] = *(const bf16x8*)&Bs[cur][(wc + j * 16 + (lane & 15)) * 64 + ko];
#pragma unroll
            for (int ii = 0; ii < 4; ++ii)
#pragma unroll
                for (int j = 0; j < 4; ++j)
                    acc[ii][j] = MFMA16(af[ii], bb[j], acc[ii][j], 0, 0, 0);
        }
    }
    const int rbase = m0 + wr + (lane >> 4) * 4;
    const int cbase = n0 + wc + (lane & 15);
#pragma unroll
    for (int j = 0; j < 4; ++j) {
        const int col = cbase + j * 16;
        const float bv = bias[col];
#pragma unroll
        for (int i = 0; i < 4; ++i)
#pragma unroll
            for (int r = 0; r < 4; ++r) {
                float v = acc[i][j][r] + bv;
                if (RELU) v = fmaxf(v, 0.f);
                C[(size_t)(rbase + i * 16 + r) * N + col] = (__bf16)v;
            }
    }
}

// ---- fused recurrent step v7: 32x128 tile, 256thr/4 waves, 2 blocks/CU ----
// Tile: 32 sorted rows x (4 gates x 32 ch = 128 gate-cols). Grid: x = colblock
// (32 of them; XCD = x%8 pins 4x256KB Whh slices = 1 MB/XCD), y = rowblock
// (skip axis). 4 waves: rh=w>>1 (16-row half), chq=w&1 (16-ch half); each wave
// holds all 4 gates of its (row,ch) in-register (4 B-frags + 1 A-frag, 4
// MFMA/ks — v5's proven per-wave shape). LDS 40 KB dbuf; BK=64, 1 barrier/iter.
__global__ __launch_bounds__(256) void lstm_step(
    const __bf16* __restrict__ h_in, const __bf16* __restrict__ Whh,
    const __bf16* __restrict__ Xg, float* __restrict__ cst,
    __bf16* __restrict__ h_out, __bf16* __restrict__ sel,
    const int* __restrict__ dl_s, const int* __restrict__ perm,
    const int* __restrict__ n_act, int t)
{
    const int nt = n_act[t];
    const int m0 = blockIdx.y * 32;        // sorted batch-row block
    if (m0 >= nt) return;                  // whole slab dead at this step
    __shared__ __bf16 As[2][32 * 64];      // 2 x 4 KB
    __shared__ __bf16 Bs[2][128 * 64];     // 2 x 16 KB
    const int tid = threadIdx.x;
    const int w = tid >> 6, lane = tid & 63;
    const int j0 = blockIdx.x * 32;        // 32-channel block
    const int rh  = w >> 1;                // row half
    const int chq = w & 1;                 // channel half

    // staging: thread -> ch-row brow (0..31) of each gate (LDS rows g*32+brow)
    // + A row brow; linear slot seg; source granule swizzled by brow&7.
    const int brow = tid >> 3;             // 0..31
    const int seg  = tid & 7;
    const int swc  = ((seg ^ (brow & 7)) << 3);
    const __bf16* gB = Whh + (size_t)(j0 + brow) * 1024 + swc;   // + g*1024*1024
    const __bf16* gA = h_in + (size_t)(m0 + brow) * 1024 + swc;

    f32x4 a0 = {0,0,0,0}, a1 = {0,0,0,0}, a2 = {0,0,0,0}, a3 = {0,0,0,0};
    bf16x8 rb0, rb1, rb2, rb3, ra;

    rb0 = *(const bf16x8*)(gB);
    rb1 = *(const bf16x8*)(gB + 1024UL * 1024);
    rb2 = *(const bf16x8*)(gB + 2048UL * 1024);
    rb3 = *(const bf16x8*)(gB + 3072UL * 1024);
    ra  = *(const bf16x8*)(gA);

    for (int k0 = 0, i = 0; k0 < 1024; k0 += 64, ++i) {
        const int cur = i & 1;
        *(bf16x8*)&Bs[cur][(0 * 32 + brow) * 64 + seg * 8] = rb0;
        *(bf16x8*)&Bs[cur][(1 * 32 + brow) * 64 + seg * 8] = rb1;
        *(bf16x8*)&Bs[cur][(2 * 32 + brow) * 64 + seg * 8] = rb2;
        *(bf16x8*)&Bs[cur][(3 * 32 + brow) * 64 + seg * 8] = rb3;
        *(bf16x8*)&As[cur][brow * 64 + seg * 8] = ra;
        if (k0 + 64 < 1024) {
            rb0 = *(const bf16x8*)(gB + k0 + 64);
            rb1 = *(const bf16x8*)(gB + 1024UL * 1024 + k0 + 64);
            rb2 = *(const bf16x8*)(gB + 2048UL * 1024 + k0 + 64);
            rb3 = *(const bf16x8*)(gB + 3072UL * 1024 + k0 + 64);
            ra  = *(const bf16x8*)(gA + k0 + 64);
        }
        __syncthreads();
#pragma unroll
        for (int ks = 0; ks < 2; ++ks) {
            const int ko = (((ks * 4 + (lane >> 4)) ^ (lane & 7)) << 3);
            bf16x8 av = *(const bf16x8*)&As[cur][(rh * 16 + (lane & 15)) * 64 + ko];
            bf16x8 b0 = *(const bf16x8*)&Bs[cur][(0 * 32 + chq * 16 + (lane & 15)) * 64 + ko];
            bf16x8 b1 = *(const bf16x8*)&Bs[cur][(1 * 32 + chq * 16 + (lane & 15)) * 64 + ko];
            bf16x8 b2 = *(const bf16x8*)&Bs[cur][(2 * 32 + chq * 16 + (lane & 15)) * 64 + ko];
            bf16x8 b3 = *(const bf16x8*)&Bs[cur][(3 * 32 + chq * 16 + (lane & 15)) * 64 + ko];
            a0 = MFMA16(av, b0, a0, 0, 0, 0);
            a1 = MFMA16(av, b1, a1, 0, 0, 0);
            a2 = MFMA16(av, b2, a2, 0, 0, 0);
            a3 = MFMA16(av, b3, a3, 0, 0, 0);
        }
    }
    // epilogue: lane owns 4 rows x 1 channel, gates = frags a0..a3 (i,f,g,o)
    const int ch  = j0 + chq * 16 + (lane & 15);
    const int rb_ = m0 + rh * 16 + (lane >> 4) * 4;
#pragma unroll
    for (int r = 0; r < 4; ++r) {
        const int b = rb_ + r;             // sorted row index
        if (b >= nt) continue;             // DEAD ROW: touch nothing (determinism)
        const __bf16* xg = Xg + (size_t)(t * 512 + b) * 4096 + ch;
        float gi = a0[r] + (float)xg[0];
        float gf = a1[r] + (float)xg[1024];
        float gg = a2[r] + (float)xg[2048];
        float go = a3[r] + (float)xg[3072];
        const size_t ix = (size_t)b * 1024 + ch;
        float cn = fsig(gf) * cst[ix] + fsig(gi) * ftanh(gg);
        cst[ix] = cn;
        float hv = fsig(go) * ftanh(cn);
        h_out[ix] = (__bf16)hv;
        if (dl_s[b] == t + 1)
            sel[(size_t)perm[b] * 1024 + ch] = (__bf16)hv;   // scatter to orig order
    }
}

// ---- final tiny layer: out[b,o] = relu(sum_k y1[b,k]*W2[o,k] + b2[o]) ----
__global__ __launch_bounds__(256) void mlp2(
    const __bf16* __restrict__ y1, const float* __restrict__ W2,
    const float* __restrict__ b2, float* __restrict__ out)
{
    int b = blockIdx.x, tid = threadIdx.x;
    float s0 = 0.f, s1 = 0.f;
    for (int k = tid; k < 1024; k += 256) {
        float v = (float)y1[(size_t)b * 1024 + k];
        s0 += v * W2[k];
        s1 += v * W2[1024 + k];
    }
#pragma unroll
    for (int o = 32; o > 0; o >>= 1) {
        s0 += __shfl_down(s0, o);
        s1 += __shfl_down(s1, o);
    }
    __shared__ float red[8];
    if ((tid & 63) == 0) { red[(tid >> 6) * 2] = s0; red[(tid >> 6) * 2 + 1] = s1; }
    __syncthreads();
    if (tid == 0) {
        float a0 = red[0] + red[2] + red[4] + red[6] + b2[0];
        float a1 = red[1] + red[3] + red[5] + red[7] + b2[1];
        out[b * 2 + 0] = fmaxf(a0, 0.f);
        out[b * 2 + 1] = fmaxf(a1, 0.f);
    }
}

extern "C" void kernel_launch(void* const* d_in, const int* in_sizes, int n_in,
                              void* d_out, int out_size, void* d_ws, size_t ws_size,
                              hipStream_t stream) {
    const int*   ent     = (const int*)d_in[0];
    const int*   rel     = (const int*)d_in[1];
    const int*   dlen    = (const int*)d_in[3];
    const float* ent_emb = (const float*)d_in[4];
    const float* rel_emb = (const float*)d_in[5];
    const float* Wih     = (const float*)d_in[6];
    const float* Whh     = (const float*)d_in[7];
    const float* bih     = (const float*)d_in[8];
    const float* bhh     = (const float*)d_in[9];
    const float* W1      = (const float*)d_in[10];
    const float* b1      = (const float*)d_in[11];
    const float* W2      = (const float*)d_in[12];
    const float* b2      = (const float*)d_in[13];
    float* out = (float*)d_out;

    char* ws = (char*)d_ws;
    size_t off = 0;
    auto alloc = [&](size_t bytes) -> void* {
        void* p = ws + off; off += (bytes + 255) & ~(size_t)255; return p;
    };
    __bf16* xbf   = (__bf16*)alloc(10240UL * 1024 * 2);  // [t*512+sb][1024]
    __bf16* Wih1  = (__bf16*)alloc(4096UL * 1024 * 2);
    __bf16* Whh1  = (__bf16*)alloc(4096UL * 1024 * 2);
    __bf16* W1b   = (__bf16*)alloc(1024UL * 1024 * 2);
    float*  bsum  = (float*) alloc(4096UL * 4);
    __bf16* Xg    = (__bf16*)alloc(10240UL * 4096 * 2);  // [t*512+sb][g*1024+ch]
    __bf16* hA    = (__bf16*)alloc(512UL * 1024 * 2);
    __bf16* hB    = (__bf16*)alloc(512UL * 1024 * 2);
    float*  cst   = (float*) alloc(512UL * 1024 * 4);
    __bf16* selb  = (__bf16*)alloc(512UL * 1024 * 2);    // ORIGINAL row order
    __bf16* y1b   = (__bf16*)alloc(512UL * 1024 * 2);
    int*    permb = (int*)   alloc(512 * 4);
    int*    dl_s  = (int*)   alloc(512 * 4);
    int*    n_act = (int*)   alloc(32 * 4);

    // merged convert + sort (independent work; sort hides under convert)
    prep<<<dim3(2049), dim3(512), 0, stream>>>(
        Wih, Whh, W1, bih, bhh, dlen,
        Wih1, Whh1, W1b, bsum, permb, dl_s, n_act);
    gather_x<<<dim3(10240), dim3(256), 0, stream>>>(
        ent, rel, ent_emb, rel_emb, permb, xbf);
    // Xg = x @ W_ih[1]^T + (b_ih+b_hh); grid x=colblock (XCD-pins B slices),
    // y=rowslab (skip axis; dead 128-row slabs exit).
    gemm_bias<false, true><<<dim3(32, 80), dim3(256), 0, stream>>>(
        xbf, Wih1, bsum, Xg, 10240, 4096, 1024, n_act);

    hipMemsetAsync(hA, 0, 512UL * 1024 * 2, stream);
    hipMemsetAsync(hB, 0, 512UL * 1024 * 2, stream);
    hipMemsetAsync(cst, 0, 512UL * 1024 * 4, stream);

    for (int t = 0; t < 20; ++t) {
        const __bf16* hi = (t & 1) ? hB : hA;
        __bf16*       ho = (t & 1) ? hA : hB;
        // grid: x = colblock (Whh slice -> XCD pin), y = rowblock (skip axis)
        lstm_step<<<dim3(32, 16), dim3(256), 0, stream>>>(
            hi, Whh1, Xg, cst, ho, selb, dl_s, permb, n_act, t);
    }

    // y1 = relu(sel @ W1^T + b1)
    gemm_bias<true, false><<<dim3(8, 4), dim3(256), 0, stream>>>(
        selb, W1b, b1, y1b, 512, 1024, 1024, nullptr);
    mlp2<<<dim3(512), dim3(256), 0, stream>>>(y1b, W2, b2, out);
}